// Round 8
// baseline (586.395 us; speedup 1.0000x reference)
//
#include <hip/hip_runtime.h>

typedef __attribute__((ext_vector_type(8))) short short8;
typedef __attribute__((ext_vector_type(4))) float f32x4;
typedef unsigned int u32;

#define DI static __device__ __forceinline__

DI unsigned short f2bf(float f) {
  unsigned u = __builtin_bit_cast(unsigned, f);
  u += 0x7fffu + ((u >> 16) & 1u);
  return (unsigned short)(u >> 16);
}
DI float bf2f(unsigned short b) {
  unsigned u = ((unsigned)b) << 16;
  return __builtin_bit_cast(float, u);
}

DI void gload16(const unsigned short* g, unsigned short* l) {
  __builtin_amdgcn_global_load_lds(
      (const __attribute__((address_space(1))) u32*)g,
      (__attribute__((address_space(3))) u32*)l, 16, 0, 0);
}

static constexpr int NT   = 2048;   // B*S tokens
static constexpr int SEQ  = 1024;
static constexpr int DIM  = 1024;
static constexpr int NH   = 16;
static constexpr int NKV  = 8;
static constexpr int HD   = 64;
static constexpr int MDIM = 3584;
static constexpr int NE   = 8;
static constexpr int QW   = 2048;      // fused qkv width
static constexpr int GUW  = 2 * MDIM;  // 7168

// ---------------------------------------------------------------- transpose+convert
__global__ void __launch_bounds__(256) transpose_kernel(
    const float* __restrict__ in, unsigned short* __restrict__ out,
    int R, int C, size_t in_estride, size_t out_estride) {
  __shared__ unsigned short tl[64][66];
  int e = blockIdx.z;
  const float* ip = in + (size_t)e * in_estride;
  unsigned short* op = out + (size_t)e * out_estride;
  int c0 = blockIdx.x * 64, r0 = blockIdx.y * 64;
  int tid = threadIdx.x;
  {
    int lr = tid >> 4, lc = (tid & 15) * 4;
#pragma unroll
    for (int p = 0; p < 4; ++p) {
      int r = p * 16 + lr;
      float4 v = *(const float4*)(ip + (size_t)(r0 + r) * C + c0 + lc);
      tl[lc + 0][r] = f2bf(v.x);
      tl[lc + 1][r] = f2bf(v.y);
      tl[lc + 2][r] = f2bf(v.z);
      tl[lc + 3][r] = f2bf(v.w);
    }
  }
  __syncthreads();
  {
    int c = tid >> 2, rc = (tid & 3) * 16;
    unsigned short tmp[16];
#pragma unroll
    for (int j = 0; j < 8; ++j) {
      u32 w = *(const u32*)&tl[c][rc + j * 2];
      tmp[j * 2] = (unsigned short)w;
      tmp[j * 2 + 1] = (unsigned short)(w >> 16);
    }
    unsigned short* dst = op + (size_t)(c0 + c) * R + r0 + rc;
#pragma unroll
    for (int j = 0; j < 2; ++j)
      *(uint4*)(dst + j * 8) = *(const uint4*)&tmp[j * 8];
  }
}

// ---------------------------------------------------------------- rmsnorm
__global__ void __launch_bounds__(256) rmsnorm_kernel(const float* __restrict__ x,
                                                      const float* __restrict__ w,
                                                      unsigned short* __restrict__ out) {
  int row = blockIdx.x;
  const float* xr = x + (size_t)row * DIM;
  int i = threadIdx.x * 4;
  float4 v = *(const float4*)(xr + i);
  float s = v.x * v.x + v.y * v.y + v.z * v.z + v.w * v.w;
  for (int o = 32; o; o >>= 1) s += __shfl_xor(s, o);
  __shared__ float red[4];
  if ((threadIdx.x & 63) == 0) red[threadIdx.x >> 6] = s;
  __syncthreads();
  s = red[0] + red[1] + red[2] + red[3];
  float r = rsqrtf(s * (1.0f / DIM) + 1e-6f);
  float4 wv = *(const float4*)(w + i);
  ushort4 o4;
  o4.x = f2bf(v.x * r * wv.x);
  o4.y = f2bf(v.y * r * wv.y);
  o4.z = f2bf(v.z * r * wv.z);
  o4.w = f2bf(v.w * r * wv.w);
  *(ushort4*)(out + (size_t)row * DIM + i) = o4;
}

// ---------------------------------------------------------------- gemmT v4b
// A: bf16 [M][K] (rows optionally gathered), B: bf16 [N][K] (pre-transposed).
// 256 thr / 4 waves (2m x 2n); tile 128 x BN where BN = NNT*32 (each n-wave
// covers NNT subtiles of 16). BK=32; 3-buffer LDS ring, 2-deep prefetch,
// counted vmcnt (T4), setprio around MFMA (T5).
// Split-K: blockIdx.z = e*ks_count + ks, each split covers K/ks_count.
// chunk^(row&3) XOR swizzle applied on global source AND LDS read.
template <int GATHER, int EPI, int NNT>
__global__ void __launch_bounds__(256) gemmT_kernel(
    const unsigned short* __restrict__ A, int lda,
    const unsigned short* __restrict__ B, int ldb, size_t b_estride,
    void* __restrict__ Cv, int ldc,
    const float* __restrict__ resid,
    int M, int K,
    const int* __restrict__ lists, const int* __restrict__ cnt,
    int ks_count, size_t ks_stride) {
  constexpr int BN = NNT * 32;          // block n-tile
  constexpr int NBLK = BN / 64;         // 64-row staging blocks of B
  int zz = blockIdx.z;
  int e = zz / ks_count, ks = zz - e * ks_count;
  int KL = K / ks_count;
  int kbase = ks * KL;

  int count = M;
  const int* lst = nullptr;
  if (GATHER != 0) {
    count = cnt[e];
    if (count <= 0) return;
    lst = lists + e * NT;
    B += b_estride * (size_t)e;
  }
  int m0 = blockIdx.y * 128;
  if (m0 >= count) return;
  int n0 = blockIdx.x * BN;

  __shared__ unsigned short sA[3][128 * 32];
  __shared__ unsigned short sB[3][BN * 32];

  int tid = threadIdx.x, w = tid >> 6, lane = tid & 63;
  int l15 = lane & 15, lhi = lane >> 4;

  int srow = w * 16 + (lane >> 2);
  int schunk = ((lane & 3) ^ ((lane >> 2) & 3)) * 8;
  const unsigned short *aSrc0, *aSrc1;
  const unsigned short* bSrc[NBLK];
  {
    int mr0 = m0 + srow, mr1 = m0 + 64 + srow;
    int ar0, ar1;
    if (GATHER == 0) { ar0 = mr0; ar1 = mr1; }
    else {
      int c0i = mr0 < count ? mr0 : count - 1;
      int c1i = mr1 < count ? mr1 : count - 1;
      int p0 = lst[c0i], p1 = lst[c1i];
      ar0 = (GATHER == 1) ? (p0 >> 1) : p0;
      ar1 = (GATHER == 1) ? (p1 >> 1) : p1;
    }
    aSrc0 = A + (size_t)ar0 * lda + kbase + schunk;
    aSrc1 = A + (size_t)ar1 * lda + kbase + schunk;
#pragma unroll
    for (int s = 0; s < NBLK; ++s)
      bSrc[s] = B + (size_t)(n0 + s * 64 + srow) * ldb + kbase + schunk;
  }
  unsigned ldst = (unsigned)(w * 16) * 32;  // element offset of wave's slab

  auto stage = [&](int buf, int k0) {
    gload16(aSrc0 + k0, &sA[buf][ldst]);
    gload16(aSrc1 + k0, &sA[buf][ldst + 64 * 32]);
#pragma unroll
    for (int s = 0; s < NBLK; ++s)
      gload16(bSrc[s] + k0, &sB[buf][ldst + s * 64 * 32]);
  };

  f32x4 acc[4][NNT] = {};
  int wm = w >> 1, wn = w & 1;
  int aoff[4], boff[NNT];
#pragma unroll
  for (int t = 0; t < 4; ++t) {
    int row = wm * 64 + t * 16 + l15;
    aoff[t] = row * 32 + ((lhi ^ (row & 3)) * 8);
  }
#pragma unroll
  for (int t = 0; t < NNT; ++t) {
    int col = wn * (BN / 2) + t * 16 + l15;
    boff[t] = col * 32 + ((lhi ^ (col & 3)) * 8);
  }

  int nsteps = KL / 32;
  // prologue: 2 tiles in flight
  stage(0, 0);
  if (nsteps > 1) stage(1, 32);

  int cur = 0, stg = 2;
  for (int t = 0; t < nsteps; ++t) {
    // wait for own tile-t loads (oldest in FIFO); keep tile t+1 in flight
    if (t + 1 < nsteps) {
      if constexpr (NNT == 8) asm volatile("s_waitcnt vmcnt(6)" ::: "memory");
      else                    asm volatile("s_waitcnt vmcnt(4)" ::: "memory");
    } else {
      asm volatile("s_waitcnt vmcnt(0)" ::: "memory");
    }
    __builtin_amdgcn_s_barrier();
    __builtin_amdgcn_sched_barrier(0);
    if (t + 2 < nsteps) stage(stg, (t + 2) * 32);  // refills buf[(t-1)%3]
    const unsigned short* pa = sA[cur];
    const unsigned short* pb = sB[cur];
    short8 af[4], bfr[NNT];
#pragma unroll
    for (int q = 0; q < 4; ++q) af[q] = *(const short8*)&pa[aoff[q]];
#pragma unroll
    for (int q = 0; q < NNT; ++q) bfr[q] = *(const short8*)&pb[boff[q]];
    __builtin_amdgcn_s_setprio(1);
#pragma unroll
    for (int mi = 0; mi < 4; ++mi)
#pragma unroll
      for (int ni = 0; ni < NNT; ++ni)
        acc[mi][ni] =
            __builtin_amdgcn_mfma_f32_16x16x32_bf16(af[mi], bfr[ni], acc[mi][ni], 0, 0, 0);
    __builtin_amdgcn_s_setprio(0);
    cur = (cur == 2) ? 0 : cur + 1;
    stg = (stg == 2) ? 0 : stg + 1;
  }

#pragma unroll
  for (int mi = 0; mi < 4; ++mi) {
#pragma unroll
    for (int r = 0; r < 4; ++r) {
      int mr = m0 + wm * 64 + mi * 16 + lhi * 4 + r;
      if (GATHER != 0 && mr >= count) continue;
      size_t crow = (GATHER != 0) ? (size_t)lst[mr] : (size_t)mr;
#pragma unroll
      for (int ni = 0; ni < NNT; ++ni) {
        int n = n0 + wn * (BN / 2) + ni * 16 + l15;
        float val = acc[mi][ni][r];
        if (EPI == 0)
          ((unsigned short*)Cv)[crow * ldc + n] = f2bf(val);
        else if (EPI == 1)
          ((float*)Cv)[crow * ldc + n] = val + resid[crow * ldc + n];
        else
          ((float*)Cv)[(size_t)ks * ks_stride + crow * ldc + n] = val;
      }
    }
  }
}

// ---------------------------------------------------------------- RoPE (in-place on fused qkv)
__global__ void __launch_bounds__(256) rope_kernel(unsigned short* __restrict__ qkv) {
  int g = blockIdx.x * 256 + threadIdx.x;
  int i = g & 31;
  int hh = (g >> 5) % (NH + NKV);
  int tok = g / (32 * (NH + NKV));
  if (tok >= NT) return;
  int s = tok & (SEQ - 1);
  float inv = exp2f((float)i * (-13.287712379549449f / 32.0f));
  float ang = (float)s * inv;
  float sn = sinf(ang);
  float c = cosf(ang);
  int col = (hh < NH) ? hh * HD : DIM + (hh - NH) * HD;
  unsigned short* ptr = qkv + (size_t)tok * QW + col;
  float a = bf2f(ptr[i]), b2 = bf2f(ptr[i + 32]);
  ptr[i] = f2bf(a * c - b2 * sn);
  ptr[i + 32] = f2bf(b2 * c + a * sn);
}

// ---------------------------------------------------------------- flash attention
__global__ void __launch_bounds__(64) attn_kernel(const unsigned short* __restrict__ qkv,
                                                  unsigned short* __restrict__ ao) {
  __shared__ unsigned short Ps[16 * 64];
  int bid = blockIdx.x;
  int qt = bid & 63;
  int h = (bid >> 6) & 15;
  int b = bid >> 10;
  int lane = threadIdx.x, l15 = lane & 15, lhi = lane >> 4;
  int q0 = qt * 16, kvh = h >> 1;
  int kcol = DIM + kvh * HD, vcol = DIM + NKV * HD + kvh * HD;

  const unsigned short* qp = qkv + ((size_t)(b * SEQ + q0 + l15)) * QW + h * HD + lhi * 8;
  short8 aq0 = *(const short8*)qp;
  short8 aq1 = *(const short8*)(qp + 32);

  float m[4] = {-1e30f, -1e30f, -1e30f, -1e30f};
  float l[4] = {0.f, 0.f, 0.f, 0.f};
  f32x4 accO[4] = {};

  int nkb = (qt >> 2) + 1;
  for (int kb_ = 0; kb_ < nkb; ++kb_) {
    int kbase = kb_ * 64;
    f32x4 s[4];
#pragma unroll
    for (int ct = 0; ct < 4; ++ct) {
      const unsigned short* kp =
          qkv + ((size_t)(b * SEQ + kbase + ct * 16 + l15)) * QW + kcol + lhi * 8;
      short8 k0v = *(const short8*)kp;
      short8 k1v = *(const short8*)(kp + 32);
      f32x4 a = {};
      a = __builtin_amdgcn_mfma_f32_16x16x32_bf16(aq0, k0v, a, 0, 0, 0);
      a = __builtin_amdgcn_mfma_f32_16x16x32_bf16(aq1, k1v, a, 0, 0, 0);
      int kpos = kbase + ct * 16 + l15;
#pragma unroll
      for (int r = 0; r < 4; ++r) {
        float v = a[r] * 0.125f;
        if (kpos > q0 + lhi * 4 + r) v = -1e30f;
        s[ct][r] = v;
      }
    }
    float nm[4], al[4], rs[4];
#pragma unroll
    for (int r = 0; r < 4; ++r) {
      float mb = fmaxf(fmaxf(s[0][r], s[1][r]), fmaxf(s[2][r], s[3][r]));
      mb = fmaxf(mb, __shfl_xor(mb, 1));
      mb = fmaxf(mb, __shfl_xor(mb, 2));
      mb = fmaxf(mb, __shfl_xor(mb, 4));
      mb = fmaxf(mb, __shfl_xor(mb, 8));
      nm[r] = fmaxf(m[r], mb);
      al[r] = __expf(m[r] - nm[r]);
      m[r] = nm[r];
      rs[r] = 0.f;
    }
#pragma unroll
    for (int ct = 0; ct < 4; ++ct) {
#pragma unroll
      for (int r = 0; r < 4; ++r) {
        float p = __expf(s[ct][r] - nm[r]);
        rs[r] += p;
        int q = lhi * 4 + r;
        Ps[q * 64 + ((ct * 16 + l15) ^ (lhi << 4))] = f2bf(p);
      }
    }
#pragma unroll
    for (int r = 0; r < 4; ++r) {
      rs[r] += __shfl_xor(rs[r], 1);
      rs[r] += __shfl_xor(rs[r], 2);
      rs[r] += __shfl_xor(rs[r], 4);
      rs[r] += __shfl_xor(rs[r], 8);
      l[r] = l[r] * al[r] + rs[r];
    }
#pragma unroll
    for (int dt = 0; dt < 4; ++dt)
#pragma unroll
      for (int r = 0; r < 4; ++r) accO[dt][r] *= al[r];

    int pswz = (l15 >> 2) << 4;
    short8 ap0 = *(const short8*)&Ps[l15 * 64 + ((lhi * 8) ^ pswz)];
    short8 ap1 = *(const short8*)&Ps[l15 * 64 + ((32 + lhi * 8) ^ pswz)];
#pragma unroll
    for (int dt = 0; dt < 4; ++dt) {
#pragma unroll
      for (int ks = 0; ks < 2; ++ks) {
        const unsigned short* vp =
            qkv + ((size_t)(b * SEQ + kbase + ks * 32 + lhi * 8)) * QW + vcol + dt * 16 + l15;
        short8 vf;
#pragma unroll
        for (int j = 0; j < 8; ++j) vf[j] = (short)vp[(size_t)j * QW];
        accO[dt] = __builtin_amdgcn_mfma_f32_16x16x32_bf16(ks ? ap1 : ap0, vf, accO[dt], 0, 0, 0);
      }
    }
  }
  float invl[4];
#pragma unroll
  for (int r = 0; r < 4; ++r) invl[r] = 1.f / l[r];
#pragma unroll
  for (int dt = 0; dt < 4; ++dt)
#pragma unroll
    for (int r = 0; r < 4; ++r)
      ao[((size_t)(b * SEQ + q0 + lhi * 4 + r)) * DIM + h * HD + dt * 16 + l15] =
          f2bf(accO[dt][r] * invl[r]);
}

// ---------------------------------------------------------------- zero counts
__global__ void zero_cnt_kernel(int* __restrict__ cnt) {
  if (threadIdx.x < NE) cnt[threadIdx.x] = 0;
}

// ---------------------------------------------------------------- router (top-2, fp32 + fp64 accum)
__global__ void __launch_bounds__(64) router_kernel(const float* __restrict__ x2,
                                                    const float* __restrict__ ln2w,
                                                    const float* __restrict__ rw,
                                                    float* __restrict__ wts,
                                                    int* __restrict__ cnt,
                                                    int* __restrict__ lists) {
  int t = blockIdx.x, lane = threadIdx.x;
  const float* xr = x2 + (size_t)t * DIM;
  float xs[16];
  double ssq = 0.0;
#pragma unroll
  for (int j = 0; j < 16; ++j) {
    xs[j] = xr[lane + j * 64];
    ssq += (double)xs[j] * xs[j];
  }
  for (int o = 32; o; o >>= 1) ssq += __shfl_xor(ssq, o);
  double r = rsqrt(ssq * (1.0 / DIM) + 1e-6);
  double p[NE] = {};
#pragma unroll
  for (int j = 0; j < 16; ++j) {
    int i = lane + j * 64;
    double hv = (double)xs[j] * r * (double)ln2w[i];
    const float* rwp = rw + (size_t)i * NE;
#pragma unroll
    for (int e = 0; e < NE; ++e) p[e] += hv * (double)rwp[e];
  }
  for (int o = 32; o; o >>= 1) {
#pragma unroll
    for (int e = 0; e < NE; ++e) p[e] += __shfl_xor(p[e], o);
  }
  if (lane == 0) {
    int i1 = 0;
    for (int e = 1; e < NE; ++e)
      if (p[e] > p[i1]) i1 = e;
    int i2 = (i1 == 0) ? 1 : 0;
    for (int e = 0; e < NE; ++e)
      if (e != i1 && p[e] > p[i2]) i2 = e;
    double mx = fmax(p[i1], p[i2]);
    double e1 = exp(p[i1] - mx), e2 = exp(p[i2] - mx);
    double inv = 1.0 / (e1 + e2);
    wts[t * 2] = (float)(e1 * inv);
    wts[t * 2 + 1] = (float)(e2 * inv);
    int pos1 = atomicAdd(&cnt[i1], 1);
    lists[i1 * NT + pos1] = t * 2;
    int pos2 = atomicAdd(&cnt[i2], 1);
    lists[i2 * NT + pos2] = t * 2 + 1;
  }
}

// ---------------------------------------------------------------- SwiGLU elementwise
__global__ void __launch_bounds__(256) swiglu_kernel(const unsigned short* __restrict__ gu,
                                                     const float* __restrict__ wts,
                                                     unsigned short* __restrict__ act) {
  size_t i = ((size_t)blockIdx.x * 256 + threadIdx.x) * 8;
  int pid = (int)(i / MDIM);
  int mcol = (int)(i - (size_t)pid * MDIM);
  float w = wts[pid];
  const unsigned short* row = gu + (size_t)pid * GUW;
  short8 g8 = *(const short8*)(row + mcol);
  short8 u8 = *(const short8*)(row + MDIM + mcol);
  short8 o8;
#pragma unroll
  for (int j = 0; j < 8; ++j) {
    float gv = bf2f((unsigned short)g8[j]);
    float uv = bf2f((unsigned short)u8[j]);
    float sv = gv / (1.f + __expf(-gv));
    o8[j] = (short)f2bf(sv * uv * w);
  }
  *(short8*)(act + i) = o8;
}

// ---------------------------------------------------------------- combine (x2 + 2 pair-slots x 2 K-splits)
__global__ void __launch_bounds__(256) combine_kernel(const float* __restrict__ x2,
                                                      const float* __restrict__ part,
                                                      float* __restrict__ out) {
  const size_t KSS = (size_t)2 * NT * DIM;
  size_t idx = ((size_t)blockIdx.x * 256 + threadIdx.x) * 4;
  size_t t = idx >> 10;
  size_t d = idx & 1023;
  float4 a = *(const float4*)(x2 + idx);
  float4 b0 = *(const float4*)(part + (t * 2) * DIM + d);
  float4 c0 = *(const float4*)(part + (t * 2 + 1) * DIM + d);
  float4 b1 = *(const float4*)(part + KSS + (t * 2) * DIM + d);
  float4 c1 = *(const float4*)(part + KSS + (t * 2 + 1) * DIM + d);
  float4 o;
  o.x = a.x + b0.x + c0.x + b1.x + c1.x;
  o.y = a.y + b0.y + c0.y + b1.y + c1.y;
  o.z = a.z + b0.z + c0.z + b1.z + c1.z;
  o.w = a.w + b0.w + c0.w + b1.w + c1.w;
  *(float4*)(out + idx) = o;
}

// ---------------------------------------------------------------- launch
extern "C" void kernel_launch(void* const* d_in, const int* in_sizes, int n_in,
                              void* d_out, int out_size, void* d_ws, size_t ws_size,
                              hipStream_t stream) {
  const float* x   = (const float*)d_in[0];
  const float* ln1 = (const float*)d_in[1];
  const float* ln2 = (const float*)d_in[2];
  const float* wq  = (const float*)d_in[3];
  const float* wk  = (const float*)d_in[4];
  const float* wv  = (const float*)d_in[5];
  const float* wo  = (const float*)d_in[6];
  const float* rw  = (const float*)d_in[7];
  const float* wg  = (const float*)d_in[8];
  const float* wu  = (const float*)d_in[9];
  const float* wd  = (const float*)d_in[10];
  float* out = (float*)d_out;

  char* p = (char*)d_ws;
  auto take = [&](size_t bytes) {
    char* q = p;
    p += (bytes + 255) & ~(size_t)255;
    return q;
  };
  // persistent
  unsigned short* wguT = (unsigned short*)take((size_t)NE * GUW * DIM * 2);   // 117 MB
  unsigned short* wdT  = (unsigned short*)take((size_t)NE * DIM * MDIM * 2);  // 59 MB
  float*          x2   = (float*)take((size_t)NT * DIM * 4);
  unsigned short* h2   = (unsigned short*)take((size_t)NT * DIM * 2);
  float*          part = (float*)take((size_t)2 * 2 * NT * DIM * 4);          // 2 K-splits
  unsigned short* act  = (unsigned short*)take((size_t)2 * NT * MDIM * 2);
  float*          wtsb = (float*)take((size_t)2 * NT * 4);
  int*            cntb = (int*)take(NE * 4);
  int*            listsb = (int*)take((size_t)NE * NT * 4);
  // overlay region X: phase A (prep/attn) then phase B (gu)
  char* X = p;
  unsigned short* wqkvT = (unsigned short*)X;                 // [2048][1024]
  unsigned short* woT   = wqkvT + (size_t)QW * DIM;           // [1024][1024]
  unsigned short* h1    = woT + (size_t)DIM * DIM;
  unsigned short* qkv   = h1 + (size_t)NT * DIM;              // [NT][2048]
  unsigned short* aob   = qkv + (size_t)NT * QW;              // [NT][1024]
  unsigned short* gu    = (unsigned short*)X;                 // [2*NT][7168]

  // ---- weight prep: transpose+convert to bf16 [N][K]
  transpose_kernel<<<dim3(16, 16, 1), 256, 0, stream>>>(wq, wqkvT, DIM, DIM, 0, 0);
  transpose_kernel<<<dim3(8, 16, 1), 256, 0, stream>>>(wk, wqkvT + (size_t)DIM * DIM, DIM, 512, 0, 0);
  transpose_kernel<<<dim3(8, 16, 1), 256, 0, stream>>>(wv, wqkvT + (size_t)(DIM + 512) * DIM, DIM, 512, 0, 0);
  transpose_kernel<<<dim3(16, 16, 1), 256, 0, stream>>>(wo, woT, DIM, DIM, 0, 0);
  transpose_kernel<<<dim3(56, 16, NE), 256, 0, stream>>>(
      wg, wguT, DIM, MDIM, (size_t)DIM * MDIM, (size_t)GUW * DIM);
  transpose_kernel<<<dim3(56, 16, NE), 256, 0, stream>>>(
      wu, wguT + (size_t)MDIM * DIM, DIM, MDIM, (size_t)DIM * MDIM, (size_t)GUW * DIM);
  transpose_kernel<<<dim3(16, 56, NE), 256, 0, stream>>>(
      wd, wdT, MDIM, DIM, (size_t)MDIM * DIM, (size_t)DIM * MDIM);

  // ---- attention block
  rmsnorm_kernel<<<NT, 256, 0, stream>>>(x, ln1, h1);
  gemmT_kernel<0, 0, 4><<<dim3(QW / 128, NT / 128, 1), 256, 0, stream>>>(
      h1, DIM, wqkvT, DIM, 0, qkv, QW, nullptr, NT, DIM, nullptr, nullptr, 1, 0);
  rope_kernel<<<(NT * (NH + NKV) * 32) / 256, 256, 0, stream>>>(qkv);
  attn_kernel<<<NT * NH / 16, 64, 0, stream>>>(qkv, aob);
  gemmT_kernel<0, 1, 4><<<dim3(DIM / 128, NT / 128, 1), 256, 0, stream>>>(
      aob, DIM, woT, DIM, 0, x2, DIM, x, NT, DIM, nullptr, nullptr, 1, 0);

  // ---- MoE block
  rmsnorm_kernel<<<NT, 256, 0, stream>>>(x2, ln2, h2);
  zero_cnt_kernel<<<1, 64, 0, stream>>>(cntb);
  router_kernel<<<NT, 64, 0, stream>>>(x2, ln2, rw, wtsb, cntb, listsb);

  // gate+up: 128x256 tile (NNT=8)
  gemmT_kernel<1, 0, 8><<<dim3(GUW / 256, 16, NE), 256, 0, stream>>>(
      h2, DIM, wguT, DIM, (size_t)GUW * DIM, gu, GUW, nullptr, 0, DIM, listsb, cntb, 1, 0);
  swiglu_kernel<<<(int)(((size_t)2 * NT * MDIM) / (256 * 8)), 256, 0, stream>>>(
      gu, wtsb, act);
  // down: split-K=2 (z = expert*2 + ks), fp32 partials
  gemmT_kernel<2, 2, 4><<<dim3(DIM / 128, 16, NE * 2), 256, 0, stream>>>(
      act, MDIM, wdT, MDIM, (size_t)DIM * MDIM, part, DIM, nullptr, 0, MDIM, listsb, cntb,
      2, (size_t)2 * NT * DIM);

  combine_kernel<<<(NT * DIM) / 1024, 256, 0, stream>>>(x2, part, out);
}

// Round 9
// 507.830 us; speedup vs baseline: 1.1547x; 1.1547x over previous
//
#include <hip/hip_runtime.h>

typedef __attribute__((ext_vector_type(8))) short short8;
typedef __attribute__((ext_vector_type(4))) float f32x4;
typedef unsigned int u32;

#define DI static __device__ __forceinline__

DI unsigned short f2bf(float f) {
  unsigned u = __builtin_bit_cast(unsigned, f);
  u += 0x7fffu + ((u >> 16) & 1u);
  return (unsigned short)(u >> 16);
}
DI float bf2f(unsigned short b) {
  unsigned u = ((unsigned)b) << 16;
  return __builtin_bit_cast(float, u);
}

DI void gload16(const unsigned short* g, unsigned short* l) {
  __builtin_amdgcn_global_load_lds(
      (const __attribute__((address_space(1))) u32*)g,
      (__attribute__((address_space(3))) u32*)l, 16, 0, 0);
}

static constexpr int NT   = 2048;   // B*S tokens
static constexpr int SEQ  = 1024;
static constexpr int DIM  = 1024;
static constexpr int NH   = 16;
static constexpr int NKV  = 8;
static constexpr int HD   = 64;
static constexpr int MDIM = 3584;
static constexpr int NE   = 8;
static constexpr int QW   = 2048;      // fused qkv width
static constexpr int GUW  = 2 * MDIM;  // 7168

// ---------------------------------------------------------------- transpose+convert
// ROWMAP: 0 = identity; 1/2 = 16-col interleave for gate(1)/up(2):
//   out row = ((c>>4)<<5) + (c&15) + (ROWMAP==2 ? 16 : 0)
template <int ROWMAP>
__global__ void __launch_bounds__(256) transpose_kernel(
    const float* __restrict__ in, unsigned short* __restrict__ out,
    int R, int C, size_t in_estride, size_t out_estride) {
  __shared__ unsigned short tl[64][66];
  int e = blockIdx.z;
  const float* ip = in + (size_t)e * in_estride;
  unsigned short* op = out + (size_t)e * out_estride;
  int c0 = blockIdx.x * 64, r0 = blockIdx.y * 64;
  int tid = threadIdx.x;
  {
    int lr = tid >> 4, lc = (tid & 15) * 4;
#pragma unroll
    for (int p = 0; p < 4; ++p) {
      int r = p * 16 + lr;
      float4 v = *(const float4*)(ip + (size_t)(r0 + r) * C + c0 + lc);
      tl[lc + 0][r] = f2bf(v.x);
      tl[lc + 1][r] = f2bf(v.y);
      tl[lc + 2][r] = f2bf(v.z);
      tl[lc + 3][r] = f2bf(v.w);
    }
  }
  __syncthreads();
  {
    int c = tid >> 2, rc = (tid & 3) * 16;
    unsigned short tmp[16];
#pragma unroll
    for (int j = 0; j < 8; ++j) {
      u32 w = *(const u32*)&tl[c][rc + j * 2];
      tmp[j * 2] = (unsigned short)w;
      tmp[j * 2 + 1] = (unsigned short)(w >> 16);
    }
    int cg = c0 + c;
    int orow;
    if (ROWMAP == 0) orow = cg;
    else orow = ((cg >> 4) << 5) + (cg & 15) + (ROWMAP == 2 ? 16 : 0);
    unsigned short* dst = op + (size_t)orow * R + r0 + rc;
#pragma unroll
    for (int j = 0; j < 2; ++j)
      *(uint4*)(dst + j * 8) = *(const uint4*)&tmp[j * 8];
  }
}

// ---------------------------------------------------------------- V transpose (bf16)
// qkv[tok][vcol + hd] -> vT[((b*NKV+kvh)*HD + hd)*SEQ + s]
__global__ void __launch_bounds__(256) vtrans_kernel(const unsigned short* __restrict__ qkv,
                                                     unsigned short* __restrict__ vT) {
  __shared__ unsigned short tl[64][66];
  int s0 = blockIdx.x * 64;
  int kvh = blockIdx.y;
  int b = blockIdx.z;
  int tid = threadIdx.x;
  {
    int r = tid >> 2, cc = (tid & 3) * 16;
    const unsigned short* src =
        qkv + ((size_t)(b * SEQ + s0 + r)) * QW + (DIM + NKV * HD + kvh * HD) + cc;
    unsigned short tmp[16];
    *(uint4*)&tmp[0] = *(const uint4*)src;
    *(uint4*)&tmp[8] = *(const uint4*)(src + 8);
#pragma unroll
    for (int j = 0; j < 16; ++j) tl[cc + j][r] = tmp[j];
  }
  __syncthreads();
  {
    int h = tid >> 2, sc = (tid & 3) * 16;
    unsigned short o[16];
#pragma unroll
    for (int j = 0; j < 16; ++j) o[j] = tl[h][sc + j];
    unsigned short* dst = vT + (((size_t)(b * NKV + kvh) * HD + h) * SEQ) + s0 + sc;
    *(uint4*)dst = *(const uint4*)&o[0];
    *(uint4*)(dst + 8) = *(const uint4*)&o[8];
  }
}

// ---------------------------------------------------------------- rmsnorm
__global__ void __launch_bounds__(256) rmsnorm_kernel(const float* __restrict__ x,
                                                      const float* __restrict__ w,
                                                      unsigned short* __restrict__ out) {
  int row = blockIdx.x;
  const float* xr = x + (size_t)row * DIM;
  int i = threadIdx.x * 4;
  float4 v = *(const float4*)(xr + i);
  float s = v.x * v.x + v.y * v.y + v.z * v.z + v.w * v.w;
  for (int o = 32; o; o >>= 1) s += __shfl_xor(s, o);
  __shared__ float red[4];
  if ((threadIdx.x & 63) == 0) red[threadIdx.x >> 6] = s;
  __syncthreads();
  s = red[0] + red[1] + red[2] + red[3];
  float r = rsqrtf(s * (1.0f / DIM) + 1e-6f);
  float4 wv = *(const float4*)(w + i);
  ushort4 o4;
  o4.x = f2bf(v.x * r * wv.x);
  o4.y = f2bf(v.y * r * wv.y);
  o4.z = f2bf(v.z * r * wv.z);
  o4.w = f2bf(v.w * r * wv.w);
  *(ushort4*)(out + (size_t)row * DIM + i) = o4;
}

// ---------------------------------------------------------------- gemmT v5
// A: bf16 [M][K] (rows optionally gathered), B: bf16 [N][K] (pre-transposed).
// 256 thr / 4 waves (2m x 2n); tile 128 x (NNT*32); BK=32; 3-buffer LDS ring,
// 2-deep prefetch, counted vmcnt (T4), setprio (T5).
// LDS slot swizzle (conflict-free): LDS[row][slot] holds global chunk
// (slot - (row>>1)) & 3; fragment read uses slot = (chunk + (row>>1)) & 3.
// EPI: 0 bf16 C; 1 fp32 C=acc+resid; 2 fp32 C=acc (split-K slot);
//      3 fused SwiGLU on 16-col-interleaved gate/up (resid = wts, C = bf16 act).
template <int GATHER, int EPI, int NNT>
__global__ void __launch_bounds__(256) gemmT_kernel(
    const unsigned short* __restrict__ A, int lda,
    const unsigned short* __restrict__ B, int ldb, size_t b_estride,
    void* __restrict__ Cv, int ldc,
    const float* __restrict__ resid,
    int M, int K,
    const int* __restrict__ lists, const int* __restrict__ cnt,
    int ks_count, size_t ks_stride) {
  constexpr int BN = NNT * 32;
  constexpr int NBLK = BN / 64;
  int zz = blockIdx.z;
  int e = zz / ks_count, ks = zz - e * ks_count;
  int KL = K / ks_count;
  int kbase = ks * KL;

  int count = M;
  const int* lst = nullptr;
  if (GATHER != 0) {
    count = cnt[e];
    if (count <= 0) return;
    lst = lists + e * NT;
    B += b_estride * (size_t)e;
  }
  int m0 = blockIdx.y * 128;
  if (m0 >= count) return;
  int n0 = blockIdx.x * BN;

  __shared__ unsigned short sA[3][128 * 32];
  __shared__ unsigned short sB[3][BN * 32];

  int tid = threadIdx.x, w = tid >> 6, lane = tid & 63;
  int l15 = lane & 15, lhi = lane >> 4;

  int srow = w * 16 + (lane >> 2);
  // staging: LDS slot = lane&3 (linear); global chunk = (slot - (row>>1)) & 3
  int schunk = (((lane & 3) - ((lane >> 3) & 3)) & 3) * 8;
  const unsigned short *aSrc0, *aSrc1;
  const unsigned short* bSrc[NBLK];
  {
    int mr0 = m0 + srow, mr1 = m0 + 64 + srow;
    int ar0, ar1;
    if (GATHER == 0) { ar0 = mr0; ar1 = mr1; }
    else {
      int c0i = mr0 < count ? mr0 : count - 1;
      int c1i = mr1 < count ? mr1 : count - 1;
      int p0 = lst[c0i], p1 = lst[c1i];
      ar0 = (GATHER == 1) ? (p0 >> 1) : p0;
      ar1 = (GATHER == 1) ? (p1 >> 1) : p1;
    }
    aSrc0 = A + (size_t)ar0 * lda + kbase + schunk;
    aSrc1 = A + (size_t)ar1 * lda + kbase + schunk;
#pragma unroll
    for (int s = 0; s < NBLK; ++s)
      bSrc[s] = B + (size_t)(n0 + s * 64 + srow) * ldb + kbase + schunk;
  }
  unsigned ldst = (unsigned)(w * 16) * 32;

  auto stage = [&](int buf, int k0) {
    gload16(aSrc0 + k0, &sA[buf][ldst]);
    gload16(aSrc1 + k0, &sA[buf][ldst + 64 * 32]);
#pragma unroll
    for (int s = 0; s < NBLK; ++s)
      gload16(bSrc[s] + k0, &sB[buf][ldst + s * 64 * 32]);
  };

  f32x4 acc[4][NNT] = {};
  int wm = w >> 1, wn = w & 1;
  // fragment reads: slot = (lhi + (l15>>1)) & 3 (row-dependent, conflict-free)
  int fslot = ((lhi + (l15 >> 1)) & 3) * 8;
  int aoff[4], boff[NNT];
#pragma unroll
  for (int t = 0; t < 4; ++t) {
    int row = wm * 64 + t * 16 + l15;
    aoff[t] = row * 32 + fslot;
  }
#pragma unroll
  for (int t = 0; t < NNT; ++t) {
    int col = wn * (BN / 2) + t * 16 + l15;
    boff[t] = col * 32 + fslot;
  }

  int nsteps = KL / 32;
  stage(0, 0);
  if (nsteps > 1) stage(1, 32);

  int cur = 0, stg = 2;
  for (int t = 0; t < nsteps; ++t) {
    if (t + 1 < nsteps) {
      if constexpr (NNT == 8) asm volatile("s_waitcnt vmcnt(6)" ::: "memory");
      else                    asm volatile("s_waitcnt vmcnt(4)" ::: "memory");
    } else {
      asm volatile("s_waitcnt vmcnt(0)" ::: "memory");
    }
    __builtin_amdgcn_s_barrier();
    __builtin_amdgcn_sched_barrier(0);
    if (t + 2 < nsteps) stage(stg, (t + 2) * 32);
    const unsigned short* pa = sA[cur];
    const unsigned short* pb = sB[cur];
    short8 af[4], bfr[NNT];
#pragma unroll
    for (int q = 0; q < 4; ++q) af[q] = *(const short8*)&pa[aoff[q]];
#pragma unroll
    for (int q = 0; q < NNT; ++q) bfr[q] = *(const short8*)&pb[boff[q]];
    __builtin_amdgcn_s_setprio(1);
#pragma unroll
    for (int mi = 0; mi < 4; ++mi)
#pragma unroll
      for (int ni = 0; ni < NNT; ++ni)
        acc[mi][ni] =
            __builtin_amdgcn_mfma_f32_16x16x32_bf16(af[mi], bfr[ni], acc[mi][ni], 0, 0, 0);
    __builtin_amdgcn_s_setprio(0);
    cur = (cur == 2) ? 0 : cur + 1;
    stg = (stg == 2) ? 0 : stg + 1;
  }

#pragma unroll
  for (int mi = 0; mi < 4; ++mi) {
#pragma unroll
    for (int r = 0; r < 4; ++r) {
      int mr = m0 + wm * 64 + mi * 16 + lhi * 4 + r;
      if (GATHER != 0 && mr >= count) continue;
      size_t crow = (GATHER != 0) ? (size_t)lst[mr] : (size_t)mr;
      if (EPI == 3) {
        float wgt = resid[crow];  // resid doubles as wts[pid]
        int colbase = (n0 + wn * (BN / 2)) >> 1;
#pragma unroll
        for (int ni = 0; ni < NNT; ni += 2) {
          float g = acc[mi][ni][r], u = acc[mi][ni + 1][r];
          float sv = g / (1.f + __expf(-g));
          ((unsigned short*)Cv)[crow * ldc + colbase + (ni >> 1) * 16 + l15] =
              f2bf(sv * u * wgt);
        }
      } else {
#pragma unroll
        for (int ni = 0; ni < NNT; ++ni) {
          int n = n0 + wn * (BN / 2) + ni * 16 + l15;
          float val = acc[mi][ni][r];
          if (EPI == 0)
            ((unsigned short*)Cv)[crow * ldc + n] = f2bf(val);
          else if (EPI == 1)
            ((float*)Cv)[crow * ldc + n] = val + resid[crow * ldc + n];
          else
            ((float*)Cv)[(size_t)ks * ks_stride + crow * ldc + n] = val;
        }
      }
    }
  }
}

// ---------------------------------------------------------------- RoPE (in-place on fused qkv)
__global__ void __launch_bounds__(256) rope_kernel(unsigned short* __restrict__ qkv) {
  int g = blockIdx.x * 256 + threadIdx.x;
  int i = g & 31;
  int hh = (g >> 5) % (NH + NKV);
  int tok = g / (32 * (NH + NKV));
  if (tok >= NT) return;
  int s = tok & (SEQ - 1);
  float inv = exp2f((float)i * (-13.287712379549449f / 32.0f));
  float ang = (float)s * inv;
  float sn = sinf(ang);
  float c = cosf(ang);
  int col = (hh < NH) ? hh * HD : DIM + (hh - NH) * HD;
  unsigned short* ptr = qkv + (size_t)tok * QW + col;
  float a = bf2f(ptr[i]), b2 = bf2f(ptr[i + 32]);
  ptr[i] = f2bf(a * c - b2 * sn);
  ptr[i + 32] = f2bf(b2 * c + a * sn);
}

// ---------------------------------------------------------------- flash attention (V from vT)
__global__ void __launch_bounds__(64) attn_kernel(const unsigned short* __restrict__ qkv,
                                                  const unsigned short* __restrict__ vT,
                                                  unsigned short* __restrict__ ao) {
  __shared__ unsigned short Ps[16 * 64];
  int bid = blockIdx.x;
  int qt = bid & 63;
  int h = (bid >> 6) & 15;
  int b = bid >> 10;
  int lane = threadIdx.x, l15 = lane & 15, lhi = lane >> 4;
  int q0 = qt * 16, kvh = h >> 1;
  int kcol = DIM + kvh * HD;

  const unsigned short* qp = qkv + ((size_t)(b * SEQ + q0 + l15)) * QW + h * HD + lhi * 8;
  short8 aq0 = *(const short8*)qp;
  short8 aq1 = *(const short8*)(qp + 32);

  const unsigned short* vbase = vT + ((size_t)(b * NKV + kvh) * HD) * SEQ;

  float m[4] = {-1e30f, -1e30f, -1e30f, -1e30f};
  float l[4] = {0.f, 0.f, 0.f, 0.f};
  f32x4 accO[4] = {};

  int nkb = (qt >> 2) + 1;
  for (int kb_ = 0; kb_ < nkb; ++kb_) {
    int kbase = kb_ * 64;
    f32x4 s[4];
#pragma unroll
    for (int ct = 0; ct < 4; ++ct) {
      const unsigned short* kp =
          qkv + ((size_t)(b * SEQ + kbase + ct * 16 + l15)) * QW + kcol + lhi * 8;
      short8 k0v = *(const short8*)kp;
      short8 k1v = *(const short8*)(kp + 32);
      f32x4 a = {};
      a = __builtin_amdgcn_mfma_f32_16x16x32_bf16(aq0, k0v, a, 0, 0, 0);
      a = __builtin_amdgcn_mfma_f32_16x16x32_bf16(aq1, k1v, a, 0, 0, 0);
      int kpos = kbase + ct * 16 + l15;
#pragma unroll
      for (int r = 0; r < 4; ++r) {
        float v = a[r] * 0.125f;
        if (kpos > q0 + lhi * 4 + r) v = -1e30f;
        s[ct][r] = v;
      }
    }
    float nm[4], al[4], rs[4];
#pragma unroll
    for (int r = 0; r < 4; ++r) {
      float mb = fmaxf(fmaxf(s[0][r], s[1][r]), fmaxf(s[2][r], s[3][r]));
      mb = fmaxf(mb, __shfl_xor(mb, 1));
      mb = fmaxf(mb, __shfl_xor(mb, 2));
      mb = fmaxf(mb, __shfl_xor(mb, 4));
      mb = fmaxf(mb, __shfl_xor(mb, 8));
      nm[r] = fmaxf(m[r], mb);
      al[r] = __expf(m[r] - nm[r]);
      m[r] = nm[r];
      rs[r] = 0.f;
    }
#pragma unroll
    for (int ct = 0; ct < 4; ++ct) {
#pragma unroll
      for (int r = 0; r < 4; ++r) {
        float p = __expf(s[ct][r] - nm[r]);
        rs[r] += p;
        int q = lhi * 4 + r;
        Ps[q * 64 + ((ct * 16 + l15) ^ (lhi << 4))] = f2bf(p);
      }
    }
#pragma unroll
    for (int r = 0; r < 4; ++r) {
      rs[r] += __shfl_xor(rs[r], 1);
      rs[r] += __shfl_xor(rs[r], 2);
      rs[r] += __shfl_xor(rs[r], 4);
      rs[r] += __shfl_xor(rs[r], 8);
      l[r] = l[r] * al[r] + rs[r];
    }
#pragma unroll
    for (int dt = 0; dt < 4; ++dt)
#pragma unroll
      for (int r = 0; r < 4; ++r) accO[dt][r] *= al[r];

    int pswz = (l15 >> 2) << 4;
    short8 ap0 = *(const short8*)&Ps[l15 * 64 + ((lhi * 8) ^ pswz)];
    short8 ap1 = *(const short8*)&Ps[l15 * 64 + ((32 + lhi * 8) ^ pswz)];
#pragma unroll
    for (int dt = 0; dt < 4; ++dt) {
#pragma unroll
      for (int ks = 0; ks < 2; ++ks) {
        const unsigned short* vp =
            vbase + ((size_t)(dt * 16 + l15)) * SEQ + kbase + ks * 32 + lhi * 8;
        short8 vf = *(const short8*)vp;
        accO[dt] = __builtin_amdgcn_mfma_f32_16x16x32_bf16(ks ? ap1 : ap0, vf, accO[dt], 0, 0, 0);
      }
    }
  }
  float invl[4];
#pragma unroll
  for (int r = 0; r < 4; ++r) invl[r] = 1.f / l[r];
#pragma unroll
  for (int dt = 0; dt < 4; ++dt)
#pragma unroll
    for (int r = 0; r < 4; ++r)
      ao[((size_t)(b * SEQ + q0 + lhi * 4 + r)) * DIM + h * HD + dt * 16 + l15] =
          f2bf(accO[dt][r] * invl[r]);
}

// ---------------------------------------------------------------- zero counts
__global__ void zero_cnt_kernel(int* __restrict__ cnt) {
  if (threadIdx.x < NE) cnt[threadIdx.x] = 0;
}

// ---------------------------------------------------------------- router (top-2, fp32 + fp64 accum)
__global__ void __launch_bounds__(64) router_kernel(const float* __restrict__ x2,
                                                    const float* __restrict__ ln2w,
                                                    const float* __restrict__ rw,
                                                    float* __restrict__ wts,
                                                    int* __restrict__ cnt,
                                                    int* __restrict__ lists) {
  int t = blockIdx.x, lane = threadIdx.x;
  const float* xr = x2 + (size_t)t * DIM;
  float xs[16];
  double ssq = 0.0;
#pragma unroll
  for (int j = 0; j < 16; ++j) {
    xs[j] = xr[lane + j * 64];
    ssq += (double)xs[j] * xs[j];
  }
  for (int o = 32; o; o >>= 1) ssq += __shfl_xor(ssq, o);
  double r = rsqrt(ssq * (1.0 / DIM) + 1e-6);
  double p[NE] = {};
#pragma unroll
  for (int j = 0; j < 16; ++j) {
    int i = lane + j * 64;
    double hv = (double)xs[j] * r * (double)ln2w[i];
    const float* rwp = rw + (size_t)i * NE;
#pragma unroll
    for (int e = 0; e < NE; ++e) p[e] += hv * (double)rwp[e];
  }
  for (int o = 32; o; o >>= 1) {
#pragma unroll
    for (int e = 0; e < NE; ++e) p[e] += __shfl_xor(p[e], o);
  }
  if (lane == 0) {
    int i1 = 0;
    for (int e = 1; e < NE; ++e)
      if (p[e] > p[i1]) i1 = e;
    int i2 = (i1 == 0) ? 1 : 0;
    for (int e = 0; e < NE; ++e)
      if (e != i1 && p[e] > p[i2]) i2 = e;
    double mx = fmax(p[i1], p[i2]);
    double e1 = exp(p[i1] - mx), e2 = exp(p[i2] - mx);
    double inv = 1.0 / (e1 + e2);
    wts[t * 2] = (float)(e1 * inv);
    wts[t * 2 + 1] = (float)(e2 * inv);
    int pos1 = atomicAdd(&cnt[i1], 1);
    lists[i1 * NT + pos1] = t * 2;
    int pos2 = atomicAdd(&cnt[i2], 1);
    lists[i2 * NT + pos2] = t * 2 + 1;
  }
}

// ---------------------------------------------------------------- combine (x2 + 2 pairs x 4 K-splits)
__global__ void __launch_bounds__(256) combine_kernel(const float* __restrict__ x2,
                                                      const float* __restrict__ part,
                                                      float* __restrict__ out) {
  const size_t KSS = (size_t)2 * NT * DIM;
  size_t idx = ((size_t)blockIdx.x * 256 + threadIdx.x) * 4;
  size_t t = idx >> 10;
  size_t d = idx & 1023;
  float4 o = *(const float4*)(x2 + idx);
#pragma unroll
  for (int s = 0; s < 4; ++s) {
    float4 b0 = *(const float4*)(part + s * KSS + (t * 2) * DIM + d);
    float4 c0 = *(const float4*)(part + s * KSS + (t * 2 + 1) * DIM + d);
    o.x += b0.x + c0.x;
    o.y += b0.y + c0.y;
    o.z += b0.z + c0.z;
    o.w += b0.w + c0.w;
  }
  *(float4*)(out + idx) = o;
}

// ---------------------------------------------------------------- launch
extern "C" void kernel_launch(void* const* d_in, const int* in_sizes, int n_in,
                              void* d_out, int out_size, void* d_ws, size_t ws_size,
                              hipStream_t stream) {
  const float* x   = (const float*)d_in[0];
  const float* ln1 = (const float*)d_in[1];
  const float* ln2 = (const float*)d_in[2];
  const float* wq  = (const float*)d_in[3];
  const float* wk  = (const float*)d_in[4];
  const float* wv  = (const float*)d_in[5];
  const float* wo  = (const float*)d_in[6];
  const float* rw  = (const float*)d_in[7];
  const float* wg  = (const float*)d_in[8];
  const float* wu  = (const float*)d_in[9];
  const float* wd  = (const float*)d_in[10];
  float* out = (float*)d_out;

  char* p = (char*)d_ws;
  auto take = [&](size_t bytes) {
    char* q = p;
    p += (bytes + 255) & ~(size_t)255;
    return q;
  };
  // persistent
  unsigned short* wguT = (unsigned short*)take((size_t)NE * GUW * DIM * 2);   // 117 MB
  unsigned short* wdT  = (unsigned short*)take((size_t)NE * DIM * MDIM * 2);  // 59 MB
  float*          x2   = (float*)take((size_t)NT * DIM * 4);
  unsigned short* h2   = (unsigned short*)take((size_t)NT * DIM * 2);
  float*          part = (float*)take((size_t)4 * 2 * NT * DIM * 4);          // 4 K-splits
  unsigned short* act  = (unsigned short*)take((size_t)2 * NT * MDIM * 2);
  float*          wtsb = (float*)take((size_t)2 * NT * 4);
  int*            cntb = (int*)take(NE * 4);
  int*            listsb = (int*)take((size_t)NE * NT * 4);
  // overlay region X (attention phase only)
  char* X = p;
  unsigned short* wqkvT = (unsigned short*)X;                 // [2048][1024]
  unsigned short* woT   = wqkvT + (size_t)QW * DIM;           // [1024][1024]
  unsigned short* h1    = woT + (size_t)DIM * DIM;
  unsigned short* qkv   = h1 + (size_t)NT * DIM;              // [NT][2048]
  unsigned short* aob   = qkv + (size_t)NT * QW;              // [NT][1024]
  unsigned short* vT    = aob + (size_t)NT * DIM;             // [B][NKV][HD][SEQ]

  // ---- weight prep: transpose+convert to bf16 [N][K]
  transpose_kernel<0><<<dim3(16, 16, 1), 256, 0, stream>>>(wq, wqkvT, DIM, DIM, 0, 0);
  transpose_kernel<0><<<dim3(8, 16, 1), 256, 0, stream>>>(wk, wqkvT + (size_t)DIM * DIM, DIM, 512, 0, 0);
  transpose_kernel<0><<<dim3(8, 16, 1), 256, 0, stream>>>(wv, wqkvT + (size_t)(DIM + 512) * DIM, DIM, 512, 0, 0);
  transpose_kernel<0><<<dim3(16, 16, 1), 256, 0, stream>>>(wo, woT, DIM, DIM, 0, 0);
  transpose_kernel<1><<<dim3(56, 16, NE), 256, 0, stream>>>(
      wg, wguT, DIM, MDIM, (size_t)DIM * MDIM, (size_t)GUW * DIM);
  transpose_kernel<2><<<dim3(56, 16, NE), 256, 0, stream>>>(
      wu, wguT, DIM, MDIM, (size_t)DIM * MDIM, (size_t)GUW * DIM);
  transpose_kernel<0><<<dim3(16, 56, NE), 256, 0, stream>>>(
      wd, wdT, MDIM, DIM, (size_t)MDIM * DIM, (size_t)DIM * MDIM);

  // ---- attention block
  rmsnorm_kernel<<<NT, 256, 0, stream>>>(x, ln1, h1);
  gemmT_kernel<0, 0, 4><<<dim3(QW / 128, NT / 128, 1), 256, 0, stream>>>(
      h1, DIM, wqkvT, DIM, 0, qkv, QW, nullptr, NT, DIM, nullptr, nullptr, 1, 0);
  rope_kernel<<<(NT * (NH + NKV) * 32) / 256, 256, 0, stream>>>(qkv);
  vtrans_kernel<<<dim3(SEQ / 64, NKV, 2), 256, 0, stream>>>(qkv, vT);
  attn_kernel<<<NT * NH / 16, 64, 0, stream>>>(qkv, vT, aob);
  gemmT_kernel<0, 1, 4><<<dim3(DIM / 128, NT / 128, 1), 256, 0, stream>>>(
      aob, DIM, woT, DIM, 0, x2, DIM, x, NT, DIM, nullptr, nullptr, 1, 0);

  // ---- MoE block
  rmsnorm_kernel<<<NT, 256, 0, stream>>>(x2, ln2, h2);
  zero_cnt_kernel<<<1, 64, 0, stream>>>(cntb);
  router_kernel<<<NT, 64, 0, stream>>>(x2, ln2, rw, wtsb, cntb, listsb);

  // gate+up with fused SwiGLU (interleaved wguT; resid = wts) -> act (bf16)
  gemmT_kernel<1, 3, 4><<<dim3(GUW / 128, 16, NE), 256, 0, stream>>>(
      h2, DIM, wguT, DIM, (size_t)GUW * DIM, act, MDIM, wtsb, 0, DIM, listsb, cntb, 1, 0);
  // down: split-K=4 (z = expert*4 + ks), fp32 partials
  gemmT_kernel<2, 2, 4><<<dim3(DIM / 128, 16, NE * 4), 256, 0, stream>>>(
      act, MDIM, wdT, MDIM, (size_t)DIM * MDIM, part, DIM, nullptr, 0, MDIM, listsb, cntb,
      4, (size_t)2 * NT * DIM);

  combine_kernel<<<(NT * DIM) / 1024, 256, 0, stream>>>(x2, part, out);
}